// Round 14
// baseline (3530.909 us; speedup 1.0000x reference)
//
#include <hip/hip_runtime.h>

typedef unsigned int u32;
typedef unsigned short u16;
typedef __attribute__((ext_vector_type(4))) u32 u32x4;
typedef __attribute__((ext_vector_type(4))) u16 u16x4;
typedef __attribute__((ext_vector_type(8))) short bf16x8;
typedef __attribute__((ext_vector_type(4))) float f32x4;
typedef __attribute__((ext_vector_type(2))) float f32x2;
typedef __attribute__((ext_vector_type(2))) _Float16 h2f;

#define NSC 2          // scan blocks
#define SLICE 128      // e per scan block

__device__ __forceinline__ u16 f2bf(float x){
  u32 u = __builtin_bit_cast(u32, x);
  u = (u + 0x7fffu + ((u >> 16) & 1u)) >> 16;
  return (u16)u;
}
__device__ __forceinline__ u16 f2h(float x){
  _Float16 h = (_Float16)x;
  return __builtin_bit_cast(u16, h);
}
__device__ __forceinline__ float h2fl(u16 v){ return (float)__builtin_bit_cast(_Float16, v); }
__device__ __forceinline__ h2f as_h2(u32 v){ return __builtin_bit_cast(h2f, v); }
__device__ __forceinline__ float sigf(float x){ return 1.0f/(1.0f + __expf(-x)); }
__device__ __forceinline__ float tanh_f(float x){ float e = __expf(2.0f*x); return 1.0f - 2.0f/(e + 1.0f); }

__device__ __forceinline__ float dot2acc(u32 a, u32 b, float acc){
#if __has_builtin(__builtin_amdgcn_fdot2)
  return __builtin_amdgcn_fdot2(as_h2(a), as_h2(b), acc, false);
#else
  h2f ha = as_h2(a), hb = as_h2(b);
  return acc + (float)ha[0]*(float)hb[0] + (float)ha[1]*(float)hb[1];
#endif
}
__device__ __forceinline__ float dot4(u32x4 u, u32x4 h, float acc){
  acc = dot2acc(u[0], h[0], acc); acc = dot2acc(u[1], h[1], acc);
  acc = dot2acc(u[2], h[2], acc); acc = dot2acc(u[3], h[3], acc);
  return acc;
}

// ---------------- conversion kernels ----------------

// x (1024 x 50001) f32 -> xb (1024 x 50176) bf16, zero-pad cols [50000,50176)
__global__ void conv_x(const float* __restrict__ x, u16* __restrict__ xb){
  int col4 = (blockIdx.x*256 + threadIdx.x)*4;   // grid (49, 1024)
  int row  = blockIdx.y;
  const float* src = x + (long)row*50001 + col4;
  u16x4 v;
  if (col4 < 50000) { v[0]=f2bf(src[0]); v[1]=f2bf(src[1]); v[2]=f2bf(src[2]); v[3]=f2bf(src[3]); }
  else { v[0]=0; v[1]=0; v[2]=0; v[3]=0; }
  *(u16x4*)(xb + (long)row*50176 + col4) = v;
}

// enc_w1 (512 x 50000) f32 -> w1b (512 x 50176) bf16 padded
__global__ void conv_w1(const float* __restrict__ w, u16* __restrict__ wb){
  int col4 = (blockIdx.x*256 + threadIdx.x)*4;   // grid (49, 512)
  int row  = blockIdx.y;
  const float* src = w + (long)row*50000 + col4;
  u16x4 v;
  if (col4 < 50000) { v[0]=f2bf(src[0]); v[1]=f2bf(src[1]); v[2]=f2bf(src[2]); v[3]=f2bf(src[3]); }
  else { v[0]=0; v[1]=0; v[2]=0; v[3]=0; }
  *(u16x4*)(wb + (long)row*50176 + col4) = v;
}

// enc_w2 (256x512), dec_w1 (512x256), gate W_w stacked -> bf16
__global__ void conv_misc(const float* __restrict__ enc_w2, const float* __restrict__ dec_w1,
                          const float* __restrict__ dw, const float* __restrict__ iw,
                          const float* __restrict__ ow, const float* __restrict__ cw,
                          u16* __restrict__ w2eb, u16* __restrict__ wd1b, u16* __restrict__ wgb){
  int idx = blockIdx.x*256 + threadIdx.x;        // grid 2048
  if (idx < 131072) {
    w2eb[idx] = f2bf(enc_w2[idx]);
  } else if (idx < 262144) {
    int i = idx - 131072;
    wd1b[i] = f2bf(dec_w1[i]);
  } else {
    int i = idx - 262144;                        // 262144 elems: wgb[o][k], o = g*256+e
    int o = i >> 8, k = i & 255;
    int g = o >> 8, e = o & 255;
    const float* W = (g==0) ? dw : (g==1) ? iw : (g==2) ? ow : cw;
    wgb[i] = f2bf(W[e*256 + k]);
  }
}

// combined gate biases: bws[o] = u_b[e] + w_b[e]
__global__ void pack_bias(const float* dub, const float* dwb, const float* iub, const float* iwb,
                          const float* oub, const float* owb, const float* cub, const float* cwb,
                          float* __restrict__ bws){
  int o = blockIdx.x*256 + threadIdx.x;          // grid 4
  int g = o >> 8, e = o & 255;
  float v;
  if      (g==0) v = dub[e] + dwb[e];
  else if (g==1) v = iub[e] + iwb[e];
  else if (g==2) v = oub[e] + owb[e];
  else           v = cub[e] + cwb[e];
  bws[o] = v;
}

// Pack U for fully-register-resident scan (NSC=2 x 1024 threads).
// Block b, thread t: c=t&3 -> k in [64c,64c+64); q=t>>2 -> local rows lr=2q+j
// (j<2). lr maps to gate g=lr>>7, element e=(lr&127)+b*128 (o = g*256+e).
// Quad qq=j*8+s: k-sub [64c+8s, +8) as 4 f16x2 words, per-thread contiguous.
__global__ void pack_u(const float* du, const float* iu, const float* ou, const float* cu,
                       u32* __restrict__ upak){
  int b = blockIdx.x;                            // grid NSC x 1024
  int t = threadIdx.x;
  int c = t & 3, q = t >> 2;
  for (int j = 0; j < 2; ++j) {
    int lr = 2*q + j;
    int g = lr >> 7, e = (lr & 127) + b*SLICE;
    const float* U = (g==0) ? du : (g==1) ? iu : (g==2) ? ou : cu;
    const float* row = U + e*256 + c*64;
    for (int s = 0; s < 8; ++s)
      for (int p = 0; p < 4; ++p) {
        u32 lo = f2h(row[s*8 + 2*p]);
        u32 hi = f2h(row[s*8 + 2*p + 1]);
        upak[((long)(b*1024 + t)*16 + j*8 + s)*4 + p] = lo | (hi << 16);
      }
  }
}

// ---------------- MFMA GEMM: C = A @ B^T, A[M][K] bf16, B[N][K] bf16 ----------------
// EPI: 0 = store f32 partial at Cf + z*1024*ldc (split-K)
//      1 = bias + relu -> bf16 Cb
//      2 = bias -> f32 Cf
//      3 = bias + sigmoid -> f32 Cf with col < nGuard
template<int EPI>
__global__ __launch_bounds__(256)
void gemm_bt(const u16* __restrict__ A, const u16* __restrict__ B,
             const float* __restrict__ bias, float* __restrict__ Cf, u16* __restrict__ Cb,
             int lda, int ldb, int ldc, int kiters, int nGuard){
  __shared__ u16 As[128*32];
  __shared__ u16 Bs[128*32];
  const int tid = threadIdx.x;
  const int l = tid & 63;
  const int w = tid >> 6;
  const int wr = w >> 1, wc = w & 1;             // 2x2 wave grid, 64x64 per wave
  const long kchunk = (long)blockIdx.z * kiters * 32;
  const u16* Ab = A + (long)blockIdx.x*128*lda + kchunk;
  const u16* Bb = B + (long)blockIdx.y*128*ldb + kchunk;
  f32x4 acc[4][4];
#pragma unroll
  for (int m=0;m<4;m++)
#pragma unroll
    for (int n=0;n<4;n++) acc[m][n] = (f32x4){0.f,0.f,0.f,0.f};

  const int lr = l & 15, lk = l >> 4;
  for (int it = 0; it < kiters; ++it) {
    {
      int s = tid;
      int row = s >> 2, kg = s & 3;
      u32x4 va = *(const u32x4*)(Ab + (long)row*lda + (long)it*32 + kg*8);
      u32x4 vb = *(const u32x4*)(Bb + (long)row*ldb + (long)it*32 + kg*8);
      int sw = ((kg + row) & 3) * 8;
      *(u32x4*)&As[row*32 + sw] = va;
      *(u32x4*)&Bs[row*32 + sw] = vb;
      s = tid + 256;
      row = s >> 2; kg = s & 3;
      va = *(const u32x4*)(Ab + (long)row*lda + (long)it*32 + kg*8);
      vb = *(const u32x4*)(Bb + (long)row*ldb + (long)it*32 + kg*8);
      sw = ((kg + row) & 3) * 8;
      *(u32x4*)&As[row*32 + sw] = va;
      *(u32x4*)&Bs[row*32 + sw] = vb;
    }
    __syncthreads();
    bf16x8 af[4], bfr[4];
#pragma unroll
    for (int m=0;m<4;m++) {
      int row = wr*64 + m*16 + lr;
      af[m] = *(const bf16x8*)&As[row*32 + (((lk + row)&3)*8)];
    }
#pragma unroll
    for (int n=0;n<4;n++) {
      int row = wc*64 + n*16 + lr;
      bfr[n] = *(const bf16x8*)&Bs[row*32 + (((lk + row)&3)*8)];
    }
#pragma unroll
    for (int m=0;m<4;m++)
#pragma unroll
      for (int n=0;n<4;n++)
        acc[m][n] = __builtin_amdgcn_mfma_f32_16x16x32_bf16(af[m], bfr[n], acc[m][n], 0, 0, 0);
    __syncthreads();
  }
#pragma unroll
  for (int m=0;m<4;m++) {
#pragma unroll
    for (int n=0;n<4;n++) {
#pragma unroll
      for (int v=0;v<4;v++) {
        int r  = wr*64 + m*16 + lk*4 + v;
        int cn = wc*64 + n*16 + lr;
        long gr = (long)blockIdx.x*128 + r;
        long gc = (long)blockIdx.y*128 + cn;
        float val = acc[m][n][v];
        if (EPI == 0) {
          Cf[((long)blockIdx.z*1024 + gr)*ldc + gc] = val;
        } else if (EPI == 1) {
          float y = val + bias[gc];
          y = y > 0.f ? y : 0.f;
          Cb[gr*ldc + gc] = f2bf(y);
        } else if (EPI == 2) {
          Cf[gr*ldc + gc] = val + bias[gc];
        } else if (EPI == 3) {
          if (gc < nGuard) Cf[gr*ldc + gc] = sigf(val + bias[gc]);
        }
      }
    }
  }
}

// sum split-K partials + bias + relu -> bf16 h1b
__global__ void reduce1(const float* __restrict__ P, const float* __restrict__ b1,
                        u16* __restrict__ h1b){
  int idx = blockIdx.x*256 + threadIdx.x;        // grid 2048 -> 524288 = 1024*512
  float s = b1[idx & 511];
#pragma unroll
  for (int kc = 0; kc < 32; ++kc) s += P[(long)kc*524288 + idx];
  h1b[idx] = f2bf(s > 0.f ? s : 0.f);
}

// ---------------- 2-block cooperative scan ----------------
// r13 post-mortem: step = ~4600 cy comm (publish->L3, ~900cy poll period,
// max-of-8 skew) + ~1300 compute; phase-A optimization moved nothing.
// r14: NSC 8->2. Per-thread U = 16 quads (r13-proven register footprint),
// ZERO LDS U. k-columns split by locality: local half of phase A runs
// while pollers wait for the remote 128 words (r11 self-validating
// protocol, unchanged). Phase B back to r2's serial form: 1 lane/element,
// hq[25] register history (static indices), literal 1/k constants -> no
// LDS in the lag loop. Peak regs ~107 < 128; waves_per_eu(4,4) pins the
// 4-waves/EU budget (r6's collapse = default-8-waves heuristic).
__global__ __launch_bounds__(1024) __attribute__((amdgpu_waves_per_eu(4,4)))
void scan_kernel(const u32* __restrict__ upak, const float* __restrict__ xw,
                 u16* __restrict__ hsb, const float* __restrict__ dec_w2,
                 u16* __restrict__ w2db, u32* __restrict__ hmail){
  __shared__ __align__(16) u16 h_lds[256];       // full h vector, f16
  __shared__ float preact[512];                  // local rows lr = g*128 + e_loc
  const int b = blockIdx.x;
  const int t = threadIdx.x;

  if (b >= NSC) {
    // dec_w2 (50000x512) f32 -> w2db (50048x512) bf16, rows >= 50000 zeroed.
    const long total = (50048L*512)/4;           // u16x4 groups
    const long stride = (long)(gridDim.x - NSC)*1024;
    for (long g2 = (long)(b-NSC)*1024 + t; g2 < total; g2 += stride) {
      long base = g2*4;
      long row = base >> 9;
      u16x4 v;
      if (row < 50000) {
        const float* s = dec_w2 + base;
        v[0]=f2bf(s[0]); v[1]=f2bf(s[1]); v[2]=f2bf(s[2]); v[3]=f2bf(s[3]);
      } else { v[0]=0; v[1]=0; v[2]=0; v[3]=0; }
      *(u16x4*)(w2db + base) = v;
    }
    return;
  }

  const int c = t & 3;                           // k-chunk [64c, 64c+64)
  const int q = t >> 2;                          // rows 2q, 2q+1 (local)
  const bool is_local  = b ? (c >= 2) : (c < 2); // k-chunk in own e-range?
  const bool is_poller = (q >= 128) && (c == (b ? 0 : 2));
  const int  poll_e    = (1-b)*SLICE + (q - 128);        // remote element
  const int  lr0 = 2*q;
  const int  o_row = ((lr0 >> 7) << 8) + (lr0 & 127) + b*SLICE; // o of row lr0

  // ---- U into registers: 16 named quads (64 u32), loaded once ----
  const long ub = (long)(b*1024 + t)*16;
#define LDQ(N) u32x4 Q##N = *(const u32x4*)(upak + (ub + (N))*4)
  LDQ(0);  LDQ(1);  LDQ(2);  LDQ(3);  LDQ(4);  LDQ(5);  LDQ(6);  LDQ(7);
  LDQ(8);  LDQ(9);  LDQ(10); LDQ(11); LDQ(12); LDQ(13); LDQ(14); LDQ(15);

  u32 hq[25];                                    // 50-lag history, f16 pairs (t<128)
#pragma unroll
  for (int i = 0; i < 25; ++i) hq[i] = 0;
  if (t < 128) ((u32*)h_lds)[t] = 0;
  __syncthreads();

#define DOQ(S, QA, QB) { u32x4 hb = *(const u32x4*)((const char*)h_lds + (c<<7) + ((S)<<4)); \
  a0 = dot4(QA, hb, a0); a1 = dot4(QB, hb, a1); }

  for (int st = 0; st < 1024; ++st) {
    f32x2 xwv = (f32x2){0.f, 0.f};
    if (c == 0) xwv = *(const f32x2*)(xw + st*1024 + o_row);
    float a0 = 0.f, a1 = 0.f;
    // ---- pollers fetch remote half of h(st); local lanes compute meanwhile ----
    if (st > 0 && is_poller) {
      const u32* wp = hmail + ((st&1)<<8) + poll_e;
      u32 v;
      do {
        v = __hip_atomic_load(wp, __ATOMIC_RELAXED, __HIP_MEMORY_SCOPE_AGENT);
      } while ((v >> 16) != (u32)st);
      h_lds[poll_e] = (u16)v;
    }
    if (is_local) {
      DOQ(0,Q0,Q8); DOQ(1,Q1,Q9); DOQ(2,Q2,Q10); DOQ(3,Q3,Q11);
      DOQ(4,Q4,Q12); DOQ(5,Q5,Q13); DOQ(6,Q6,Q14); DOQ(7,Q7,Q15);
    }
    __syncthreads();                             // remote h_lds half ready
    if (!is_local) {
      DOQ(0,Q0,Q8); DOQ(1,Q1,Q9); DOQ(2,Q2,Q10); DOQ(3,Q3,Q11);
      DOQ(4,Q4,Q12); DOQ(5,Q5,Q13); DOQ(6,Q6,Q14); DOQ(7,Q7,Q15);
    }
    a0 += __shfl_xor(a0,1); a0 += __shfl_xor(a0,2);
    a1 += __shfl_xor(a1,1); a1 += __shfl_xor(a1,2);
    if (c == 0) { preact[lr0] = a0 + xwv[0]; preact[lr0+1] = a1 + xwv[1]; }
    __syncthreads();

    // ---- phase B (t<128): serial r2 form, register history, literal 1/k ----
    if (t < 128) {
      float pd = preact[t]       ;
      float pi = preact[128 + t] ;
      float po = preact[256 + t] ;
      float pc = preact[384 + t] ;
      float d  = 0.5f * sigf(pd);
      float gi = sigf(pi);
      float go = sigf(po);
      float ct = tanh_f(pc);
      float cur = gi * ct;
      // mem = sum_k w_k*hist_k; w_0=1, w_k = w_{k-1}*((d+k-1)/k) (== gammaln ratio)
      float mem0 = cur, mem1 = 0.0f;
      float wk = 1.0f;
#pragma unroll
      for (int k = 1; k < 50; ++k) {
        wk *= (d + (float)(k-1)) * (1.0f/(float)k);
        u32 pair = hq[(k-1) >> 1];
        float hv = ((k-1) & 1) ? (float)as_h2(pair)[1] : (float)as_h2(pair)[0];
        if (k & 1) mem1 += wk * hv; else mem0 += wk * hv;
      }
      float hnew = go * tanh_f(mem0 + mem1);
      // shift history (packed f16 pairs), insert cur at age 0
#pragma unroll
      for (int i = 24; i >= 1; --i) hq[i] = (hq[i] << 16) | (hq[i-1] >> 16);
      hq[0] = (hq[0] << 16) | (u32)f2h(cur);
      int eo = b*SLICE + t;
      // publish FIRST (critical path), then local stores
      __hip_atomic_store(hmail + ((((st+1)&1))<<8) + eo,
                         (((u32)(st+1)) << 16) | (u32)f2h(hnew),
                         __ATOMIC_RELAXED, __HIP_MEMORY_SCOPE_AGENT);
      h_lds[eo] = f2h(hnew);
      hsb[st*256 + eo] = f2bf(hnew);
    }
    __syncthreads();                             // own h_lds half visible next step
  }
}

// ---------------- launcher ----------------
extern "C" void kernel_launch(void* const* d_in, const int* in_sizes, int n_in,
                              void* d_out, int out_size, void* d_ws, size_t ws_size,
                              hipStream_t stream){
  const float* x      = (const float*)d_in[0];
  const float* enc_w1 = (const float*)d_in[1];
  const float* enc_b1 = (const float*)d_in[2];
  const float* enc_w2 = (const float*)d_in[3];
  const float* enc_b2 = (const float*)d_in[4];
  const float* d_u_w  = (const float*)d_in[5];  const float* d_u_b = (const float*)d_in[6];
  const float* d_w_w  = (const float*)d_in[7];  const float* d_w_b = (const float*)d_in[8];
  const float* i_u_w  = (const float*)d_in[9];  const float* i_u_b = (const float*)d_in[10];
  const float* i_w_w  = (const float*)d_in[11]; const float* i_w_b = (const float*)d_in[12];
  const float* o_u_w  = (const float*)d_in[13]; const float* o_u_b = (const float*)d_in[14];
  const float* o_w_w  = (const float*)d_in[15]; const float* o_w_b = (const float*)d_in[16];
  const float* c_u_w  = (const float*)d_in[17]; const float* c_u_b = (const float*)d_in[18];
  const float* c_w_w  = (const float*)d_in[19]; const float* c_w_b = (const float*)d_in[20];
  const float* dec_w1 = (const float*)d_in[21]; const float* dec_b1 = (const float*)d_in[22];
  const float* dec_w2 = (const float*)d_in[23]; const float* dec_b2 = (const float*)d_in[24];

  char* ws = (char*)d_ws;
  u16*   xb     = (u16*)(ws + 0L);                 // 1024*50176*2
  u16*   w1b    = (u16*)(ws + 102760448L);         // 512*50176*2
  u16*   w2db   = (u16*)(ws + 154140672L);         // 50048*512*2
  u16*   h1b    = (u16*)(ws + 205389824L);         // 1024*512*2
  u16*   e_b    = (u16*)(ws + 206438400L);         // 1024*256*2
  u16*   wgb    = (u16*)(ws + 206962688L);         // 1024*256*2
  u16*   w2eb   = (u16*)(ws + 207486976L);         // 256*512*2
  u16*   wd1b   = (u16*)(ws + 207749120L);         // 512*256*2
  u16*   d1b    = (u16*)(ws + 208011264L);         // 1024*512*2
  u16*   hsb    = (u16*)(ws + 209059840L);         // 1024*256*2
  float* xw     = (float*)(ws + 209584128L);       // 1024*1024*4
  float* bws    = (float*)(ws + 213778432L);       // 1024*4
  u32*   upak   = (u32*)(ws + 213782528L);         // NSC*1024*16*4 u32 = 524288 B
  float* out    = (float*)d_out;
  float* P      = (float*)d_out;                   // split-K partials (67 MB) reuse d_out
  // self-validating mailbox in the tail of d_out (overwritten only by the
  // decoder GEMM, which runs after the scan): 2 parities x 256 u32
  u32*   hmail  = (u32*)((char*)d_out + 200000000L); // 2048 B

  hipMemsetAsync(hmail, 0, 2048, stream);          // tag 0 never matches st >= 1

  conv_x   <<<dim3(49,1024), 256, 0, stream>>>(x, xb);
  conv_w1  <<<dim3(49,512),  256, 0, stream>>>(enc_w1, w1b);
  conv_misc<<<2048, 256, 0, stream>>>(enc_w2, dec_w1, d_w_w, i_w_w, o_w_w, c_w_w, w2eb, wd1b, wgb);
  pack_bias<<<4, 256, 0, stream>>>(d_u_b, d_w_b, i_u_b, i_w_b, o_u_b, o_w_b, c_u_b, c_w_b, bws);
  pack_u   <<<NSC, 1024, 0, stream>>>(d_u_w, i_u_w, o_u_w, c_u_w, upak);

  gemm_bt<0><<<dim3(8,4,32), 256, 0, stream>>>(xb, w1b, nullptr, P, nullptr, 50176, 50176, 512, 49, 0);
  reduce1<<<2048, 256, 0, stream>>>(P, enc_b1, h1b);
  gemm_bt<1><<<dim3(8,2,1), 256, 0, stream>>>(h1b, w2eb, enc_b2, nullptr, e_b, 512, 512, 256, 16, 0);
  gemm_bt<2><<<dim3(8,8,1), 256, 0, stream>>>(e_b, wgb, bws, xw, nullptr, 256, 256, 1024, 8, 0);
  // cooperative scan (blocks 0..1) + dec_w2 bf16 convert (blocks 2..196)
  scan_kernel<<<197, 1024, 0, stream>>>(upak, xw, hsb, dec_w2, w2db, hmail);
  gemm_bt<1><<<dim3(8,4,1), 256, 0, stream>>>(hsb, wd1b, dec_b1, nullptr, d1b, 256, 256, 512, 8, 0);
  gemm_bt<3><<<dim3(8,391,1), 256, 0, stream>>>(d1b, w2db, dec_b2, out, nullptr, 512, 512, 50000, 16, 50000);
}